// Round 1
// baseline (62.363 us; speedup 1.0000x reference)
//
#include <hip/hip_runtime.h>

#define H 128
#define N 1024

// ---------------------------------------------------------------------------
// Kernel 1 (prep): per 8 rows —
//   e = x / max(||x||,1e-12)
//   Lp[i][h] = b1[h] + sum_k e[i][k]*W1[k][h]        (b1 folded in)
//   Rt[h][i] =         sum_k e[i][k]*W1[H+k][h]      (stored transposed)
// grid: N/8 blocks x 128 threads
// ---------------------------------------------------------------------------
__global__ __launch_bounds__(128) void prep_kernel(
    const float* __restrict__ x, const float* __restrict__ W1,
    const float* __restrict__ b1, float* __restrict__ Lp,
    float* __restrict__ Rt)
{
    constexpr int ROWS = 8;
    __shared__ float e_s[ROWS][H];
    __shared__ float red[ROWS][2];
    const int t = threadIdx.x;
    const int i0 = blockIdx.x * ROWS;

    float v[ROWS];
#pragma unroll
    for (int ii = 0; ii < ROWS; ++ii) v[ii] = x[(i0 + ii) * H + t];

#pragma unroll
    for (int ii = 0; ii < ROWS; ++ii) {
        float s = v[ii] * v[ii];
#pragma unroll
        for (int off = 32; off; off >>= 1) s += __shfl_xor(s, off);
        if ((t & 63) == 0) red[ii][t >> 6] = s;
    }
    __syncthreads();
#pragma unroll
    for (int ii = 0; ii < ROWS; ++ii) {
        float rn = 1.0f / fmaxf(sqrtf(red[ii][0] + red[ii][1]), 1e-12f);
        e_s[ii][t] = v[ii] * rn;
    }
    __syncthreads();

    float accL[ROWS], accR[ROWS];
    const float bb = b1[t];
#pragma unroll
    for (int ii = 0; ii < ROWS; ++ii) { accL[ii] = bb; accR[ii] = 0.f; }

    for (int k = 0; k < H; ++k) {
        const float wl = W1[k * H + t];
        const float wr = W1[(H + k) * H + t];
#pragma unroll
        for (int ii = 0; ii < ROWS; ++ii) {
            const float ev = e_s[ii][k];
            accL[ii] = fmaf(ev, wl, accL[ii]);
            accR[ii] = fmaf(ev, wr, accR[ii]);
        }
    }
#pragma unroll
    for (int ii = 0; ii < ROWS; ++ii) {
        Lp[(i0 + ii) * H + t] = accL[ii];
        Rt[t * N + (i0 + ii)] = accR[ii];
    }
}

// ---------------------------------------------------------------------------
// Kernel 2 (main): block = 4 rows i, 256 threads, thread = 4 consecutive j.
//   logits[i][j] = sum_h relu(Lp[i][h] + Rt[h][j]) * w2[h]   (b2 cancels)
//   out[i][:]    = softmax_j(logits[i][:])   — block-local reductions
// grid: N/4 blocks x 256 threads
// ---------------------------------------------------------------------------
__global__ __launch_bounds__(256) void adj_kernel(
    const float* __restrict__ Lp, const float* __restrict__ Rt,
    const float* __restrict__ W2, float* __restrict__ out)
{
    constexpr int II = 4;   // rows per block
    constexpr int JJ = 4;   // cols per thread
    __shared__ float Ls[II][H];
    __shared__ float w2s[H];
    __shared__ float red_m[II][4];
    __shared__ float red_s[II][4];

    const int t = threadIdx.x;
    const int lane = t & 63, wave = t >> 6;
    const int i0 = blockIdx.x * II;
    const int j0 = t * JJ;

    if (t < H) w2s[t] = W2[t];
#pragma unroll
    for (int ii = 0; ii < II; ++ii)
        if (t < H) Ls[ii][t] = Lp[(i0 + ii) * H + t];
    __syncthreads();

    float acc[II][JJ];
#pragma unroll
    for (int ii = 0; ii < II; ++ii)
#pragma unroll
        for (int jj = 0; jj < JJ; ++jj) acc[ii][jj] = 0.f;

#pragma unroll 8
    for (int h = 0; h < H; ++h) {
        const float4 r = *reinterpret_cast<const float4*>(&Rt[h * N + j0]);
        const float w = w2s[h];
#pragma unroll
        for (int ii = 0; ii < II; ++ii) {
            const float lv = Ls[ii][h];
            acc[ii][0] = fmaf(fmaxf(lv + r.x, 0.f), w, acc[ii][0]);
            acc[ii][1] = fmaf(fmaxf(lv + r.y, 0.f), w, acc[ii][1]);
            acc[ii][2] = fmaf(fmaxf(lv + r.z, 0.f), w, acc[ii][2]);
            acc[ii][3] = fmaf(fmaxf(lv + r.w, 0.f), w, acc[ii][3]);
        }
    }

    // ---- block softmax: max ----
#pragma unroll
    for (int ii = 0; ii < II; ++ii) {
        float m = fmaxf(fmaxf(acc[ii][0], acc[ii][1]),
                        fmaxf(acc[ii][2], acc[ii][3]));
#pragma unroll
        for (int off = 32; off; off >>= 1) m = fmaxf(m, __shfl_xor(m, off));
        if (lane == 0) red_m[ii][wave] = m;
    }
    __syncthreads();

    float mm[II];
#pragma unroll
    for (int ii = 0; ii < II; ++ii)
        mm[ii] = fmaxf(fmaxf(red_m[ii][0], red_m[ii][1]),
                       fmaxf(red_m[ii][2], red_m[ii][3]));

    // ---- exp + sum ----
#pragma unroll
    for (int ii = 0; ii < II; ++ii) {
        float s = 0.f;
#pragma unroll
        for (int jj = 0; jj < JJ; ++jj) {
            acc[ii][jj] = expf(acc[ii][jj] - mm[ii]);
            s += acc[ii][jj];
        }
#pragma unroll
        for (int off = 32; off; off >>= 1) s += __shfl_xor(s, off);
        if (lane == 0) red_s[ii][wave] = s;
    }
    __syncthreads();

#pragma unroll
    for (int ii = 0; ii < II; ++ii) {
        const float s = red_s[ii][0] + red_s[ii][1] + red_s[ii][2] + red_s[ii][3];
        const float r = 1.0f / s;
        float4 o;
        o.x = acc[ii][0] * r; o.y = acc[ii][1] * r;
        o.z = acc[ii][2] * r; o.w = acc[ii][3] * r;
        *reinterpret_cast<float4*>(&out[(i0 + ii) * N + j0]) = o;
    }
}

extern "C" void kernel_launch(void* const* d_in, const int* in_sizes, int n_in,
                              void* d_out, int out_size, void* d_ws, size_t ws_size,
                              hipStream_t stream) {
    const float* x  = (const float*)d_in[0];   // (N,H)
    const float* W1 = (const float*)d_in[1];   // (2H,H)
    const float* b1 = (const float*)d_in[2];   // (H,)
    const float* W2 = (const float*)d_in[3];   // (H,1)
    // d_in[4] = b2 — cancels under softmax (shift invariance), not needed.
    float* out = (float*)d_out;

    float* Lp = (float*)d_ws;        // N*H floats
    float* Rt = Lp + N * H;          // H*N floats (transposed)

    prep_kernel<<<N / 8, 128, 0, stream>>>(x, W1, b1, Lp, Rt);
    adj_kernel<<<N / 4, 256, 0, stream>>>(Lp, Rt, W2, out);
}

// Round 2
// 35.774 us; speedup vs baseline: 1.7433x; 1.7433x over previous
//
#include <hip/hip_runtime.h>

#define H 128
#define N 1024

// ---------------------------------------------------------------------------
// Kernel 1 (prep): 4 rows/block, 256 threads.
//   Phase 1: wave w L2-normalizes row w (pure shuffle reduce, no LDS).
//   Phase 2: thread t: h = t&127, half = t>>7 (0->L, 1->R).
//            acc[r] += e[r][k] * W1[(half*H+k)*H + h], depth-8 prefetch on W1.
//   Lp[i][h] = L + b1[h];  Rt[h][i] = R (transposed for kernel 2).
// grid: N/4 = 256 blocks
// ---------------------------------------------------------------------------
__global__ __launch_bounds__(256) void prep_kernel(
    const float* __restrict__ x, const float* __restrict__ W1,
    const float* __restrict__ b1, float* __restrict__ Lp,
    float* __restrict__ Rt)
{
    constexpr int ROWS = 4;
    constexpr int PF = 8;
    __shared__ float e_s[ROWS][H];
    const int t = threadIdx.x;
    const int i0 = blockIdx.x * ROWS;

    // ---- phase 1: normalize (wave w owns row w) ----
    {
        const int row = t >> 6, lane = t & 63;
        const float2 v = *reinterpret_cast<const float2*>(&x[(i0 + row) * H + 2 * lane]);
        float s = v.x * v.x + v.y * v.y;
#pragma unroll
        for (int off = 32; off; off >>= 1) s += __shfl_xor(s, off);
        const float rn = 1.0f / fmaxf(sqrtf(s), 1e-12f);
        e_s[row][2 * lane]     = v.x * rn;
        e_s[row][2 * lane + 1] = v.y * rn;
    }
    __syncthreads();

    // ---- phase 2: dual GEMM with register-pipelined W1 loads ----
    const int h = t & (H - 1);
    const int half = t >> 7;                    // 0 -> L, 1 -> R
    const float* Wb = W1 + half * H * H + h;    // W1[(half*H + k)*H + h]

    float acc[ROWS] = {0.f, 0.f, 0.f, 0.f};
    float wbuf[PF];
#pragma unroll
    for (int p = 0; p < PF; ++p) wbuf[p] = Wb[p * H];

    for (int kb = 0; kb < H - PF; kb += PF) {
#pragma unroll
        for (int p = 0; p < PF; ++p) {
            const float w = wbuf[p];
            wbuf[p] = Wb[(kb + p + PF) * H];
#pragma unroll
            for (int r = 0; r < ROWS; ++r)
                acc[r] = fmaf(e_s[r][kb + p], w, acc[r]);
        }
    }
#pragma unroll
    for (int p = 0; p < PF; ++p) {              // tail, no prefetch
        const int k = H - PF + p;
#pragma unroll
        for (int r = 0; r < ROWS; ++r)
            acc[r] = fmaf(e_s[r][k], wbuf[p], acc[r]);
    }

    if (half == 0) {
        const float bb = b1[h];
#pragma unroll
        for (int r = 0; r < ROWS; ++r) Lp[(i0 + r) * H + h] = acc[r] + bb;
    } else {
#pragma unroll
        for (int r = 0; r < ROWS; ++r) Rt[h * N + (i0 + r)] = acc[r];
    }
}

// ---------------------------------------------------------------------------
// Kernel 2 (main): block = 4 rows i, 256 threads, thread = 4 consecutive j.
//   logits[i][j] = sum_h relu(Lp[i][h] + Rt[h][j]) * w2[h]   (b2 cancels)
//   softmax over j, block-local. Register-pipelined Rt loads (PF=4 float4
//   in flight) so the loop is VALU-issue-bound, not L2-latency-bound.
// grid: N/4 = 256 blocks
// ---------------------------------------------------------------------------
__global__ __launch_bounds__(256) void adj_kernel(
    const float* __restrict__ Lp, const float* __restrict__ Rt,
    const float* __restrict__ W2, float* __restrict__ out)
{
    constexpr int II = 4;   // rows per block
    constexpr int JJ = 4;   // cols per thread
    constexpr int PF = 4;   // float4 loads in flight
    __shared__ float LsT[H][II];       // transposed: one b128 read per h
    __shared__ float w2s[H];
    __shared__ float red_m[II][4];
    __shared__ float red_s[II][4];

    const int t = threadIdx.x;
    const int lane = t & 63, wave = t >> 6;
    const int i0 = blockIdx.x * II;
    const int j0 = t * JJ;

    if (t < H) {
        w2s[t] = W2[t];
        float4 lv;
        lv.x = Lp[(i0 + 0) * H + t];
        lv.y = Lp[(i0 + 1) * H + t];
        lv.z = Lp[(i0 + 2) * H + t];
        lv.w = Lp[(i0 + 3) * H + t];
        *reinterpret_cast<float4*>(&LsT[t][0]) = lv;
    }
    __syncthreads();

    float acc[II][JJ];
#pragma unroll
    for (int ii = 0; ii < II; ++ii)
#pragma unroll
        for (int jj = 0; jj < JJ; ++jj) acc[ii][jj] = 0.f;

    float4 rbuf[PF];
#pragma unroll
    for (int p = 0; p < PF; ++p)
        rbuf[p] = *reinterpret_cast<const float4*>(&Rt[p * N + j0]);

    for (int hb = 0; hb < H - PF; hb += PF) {
#pragma unroll
        for (int p = 0; p < PF; ++p) {
            const int h = hb + p;
            const float4 r = rbuf[p];
            rbuf[p] = *reinterpret_cast<const float4*>(&Rt[(h + PF) * N + j0]);
            const float4 lv4 = *reinterpret_cast<const float4*>(&LsT[h][0]);
            const float w = w2s[h];
            const float* lvp = &lv4.x;
            const float* rp  = &r.x;
#pragma unroll
            for (int ii = 0; ii < II; ++ii) {
                const float lv = lvp[ii];
#pragma unroll
                for (int jj = 0; jj < JJ; ++jj)
                    acc[ii][jj] = fmaf(fmaxf(lv + rp[jj], 0.f), w, acc[ii][jj]);
            }
        }
    }
#pragma unroll
    for (int p = 0; p < PF; ++p) {              // tail, no prefetch
        const int h = H - PF + p;
        const float4 r = rbuf[p];
        const float4 lv4 = *reinterpret_cast<const float4*>(&LsT[h][0]);
        const float w = w2s[h];
        const float* lvp = &lv4.x;
        const float* rp  = &r.x;
#pragma unroll
        for (int ii = 0; ii < II; ++ii) {
            const float lv = lvp[ii];
#pragma unroll
            for (int jj = 0; jj < JJ; ++jj)
                acc[ii][jj] = fmaf(fmaxf(lv + rp[jj], 0.f), w, acc[ii][jj]);
        }
    }

    // ---- block softmax: max ----
#pragma unroll
    for (int ii = 0; ii < II; ++ii) {
        float m = fmaxf(fmaxf(acc[ii][0], acc[ii][1]),
                        fmaxf(acc[ii][2], acc[ii][3]));
#pragma unroll
        for (int off = 32; off; off >>= 1) m = fmaxf(m, __shfl_xor(m, off));
        if (lane == 0) red_m[ii][wave] = m;
    }
    __syncthreads();

    float mm[II];
#pragma unroll
    for (int ii = 0; ii < II; ++ii)
        mm[ii] = fmaxf(fmaxf(red_m[ii][0], red_m[ii][1]),
                       fmaxf(red_m[ii][2], red_m[ii][3]));

    // ---- exp + sum ----
#pragma unroll
    for (int ii = 0; ii < II; ++ii) {
        float s = 0.f;
#pragma unroll
        for (int jj = 0; jj < JJ; ++jj) {
            acc[ii][jj] = expf(acc[ii][jj] - mm[ii]);
            s += acc[ii][jj];
        }
#pragma unroll
        for (int off = 32; off; off >>= 1) s += __shfl_xor(s, off);
        if (lane == 0) red_s[ii][wave] = s;
    }
    __syncthreads();

#pragma unroll
    for (int ii = 0; ii < II; ++ii) {
        const float s = red_s[ii][0] + red_s[ii][1] + red_s[ii][2] + red_s[ii][3];
        const float r = 1.0f / s;
        float4 o;
        o.x = acc[ii][0] * r; o.y = acc[ii][1] * r;
        o.z = acc[ii][2] * r; o.w = acc[ii][3] * r;
        *reinterpret_cast<float4*>(&out[(i0 + ii) * N + j0]) = o;
    }
}

extern "C" void kernel_launch(void* const* d_in, const int* in_sizes, int n_in,
                              void* d_out, int out_size, void* d_ws, size_t ws_size,
                              hipStream_t stream) {
    const float* x  = (const float*)d_in[0];   // (N,H)
    const float* W1 = (const float*)d_in[1];   // (2H,H)
    const float* b1 = (const float*)d_in[2];   // (H,)
    const float* W2 = (const float*)d_in[3];   // (H,1)
    // d_in[4] = b2 — cancels under softmax (shift invariance), not needed.
    float* out = (float*)d_out;

    float* Lp = (float*)d_ws;        // N*H floats
    float* Rt = Lp + N * H;          // H*N floats (transposed)

    prep_kernel<<<N / 4, 256, 0, stream>>>(x, W1, b1, Lp, Rt);
    adj_kernel<<<N / 4, 256, 0, stream>>>(Lp, Rt, W2, out);
}

// Round 3
// 25.582 us; speedup vs baseline: 2.4378x; 1.3984x over previous
//
#include <hip/hip_runtime.h>

#define H 128
#define N 1024

// ---------------------------------------------------------------------------
// prep: grid N/4 = 256 blocks x 512 threads (8 waves -> 8 waves/CU).
//   phase 1: waves 0-3 L2-normalize rows 0-3 (shuffle reduce).
//   phase 2: quarter q = t>>7: q<2 -> L-half of W1, q>=2 -> R-half;
//            rows {0,1} (q even) or {2,3} (q odd); h = t&127.
//            PF=8 register-pipelined W1 column loads.
//   Outputs (all scaled by w2[h], so relu(x)*w2 = s*|u| works downstream):
//     Lp[i][h] = w2[h]*(L[i][h] + b1[h])
//     Rt[h][j] = w2[h]*R[j][h]          (transposed for adj)
//     c[j]     = 0.5 * sum_h Rt[h][j]   (softmax-invariant part of logits)
// ---------------------------------------------------------------------------
__global__ __launch_bounds__(512) void prep_kernel(
    const float* __restrict__ x, const float* __restrict__ W1,
    const float* __restrict__ b1, const float* __restrict__ W2,
    float* __restrict__ Lp, float* __restrict__ Rt, float* __restrict__ c)
{
    constexpr int PF = 8;
    __shared__ float e_s[4][H];
    __shared__ float cred[4][2];
    const int t = threadIdx.x;
    const int i0 = blockIdx.x * 4;

    if (t < 256) {                       // normalize: wave w owns row w
        const int row = t >> 6, lane = t & 63;
        const float2 v = *reinterpret_cast<const float2*>(&x[(i0 + row) * H + 2 * lane]);
        float s = v.x * v.x + v.y * v.y;
#pragma unroll
        for (int off = 32; off; off >>= 1) s += __shfl_xor(s, off);
        const float rn = 1.0f / fmaxf(sqrtf(s), 1e-12f);
        e_s[row][2 * lane]     = v.x * rn;
        e_s[row][2 * lane + 1] = v.y * rn;
    }
    __syncthreads();

    const int h = t & (H - 1);
    const int q = t >> 7;                // 0,1 -> L ; 2,3 -> R
    const int r0 = (q & 1) * 2;          // row pair {0,1} or {2,3}
    const float* Wb = W1 + (q >= 2 ? H * H : 0) + h;

    float acc0 = 0.f, acc1 = 0.f;
    float wbuf[PF];
#pragma unroll
    for (int p = 0; p < PF; ++p) wbuf[p] = Wb[p * H];

    for (int kb = 0; kb < H - PF; kb += PF) {
#pragma unroll
        for (int p = 0; p < PF; ++p) {
            const float w = wbuf[p];
            wbuf[p] = Wb[(kb + p + PF) * H];
            acc0 = fmaf(e_s[r0][kb + p],     w, acc0);
            acc1 = fmaf(e_s[r0 + 1][kb + p], w, acc1);
        }
    }
#pragma unroll
    for (int p = 0; p < PF; ++p) {
        const int k = H - PF + p;
        acc0 = fmaf(e_s[r0][k],     wbuf[p], acc0);
        acc1 = fmaf(e_s[r0 + 1][k], wbuf[p], acc1);
    }

    const float w2h = W2[h];
    if (q < 2) {
        const float bb = b1[h];
        Lp[(i0 + r0) * H + h]     = w2h * (acc0 + bb);
        Lp[(i0 + r0 + 1) * H + h] = w2h * (acc1 + bb);
    } else {
        const float v0 = w2h * acc0, v1 = w2h * acc1;
        Rt[h * N + (i0 + r0)]     = v0;
        Rt[h * N + (i0 + r0 + 1)] = v1;
        float s0 = v0, s1 = v1;          // c_j partial sums over h
#pragma unroll
        for (int off = 32; off; off >>= 1) {
            s0 += __shfl_xor(s0, off);
            s1 += __shfl_xor(s1, off);
        }
        const int wv = t >> 6;           // 4..7
        if ((t & 63) == 0) { cred[wv - 4][0] = s0; cred[wv - 4][1] = s1; }
    }
    __syncthreads();
    if (t < 4) {                         // c[i0+r]: combine the 2 waves per row
        const int r = t;
        c[i0 + r] = 0.5f * (cred[(r >> 1) * 2][r & 1] + cred[(r >> 1) * 2 + 1][r & 1]);
    }
}

// ---------------------------------------------------------------------------
// adj: grid N/4 = 256 blocks x 512 threads (8 waves -> 2 waves/SIMD).
//   thread t: rows i0..i0+3, cols j0 = 2t, 2t+1.
//   logit'[i][j] = c[j] + sum_h s_h * |Lp[i][h] + Rt[h][j]|,  s_h = ±0.5
//   (exactly sum_h relu(L+R+b1)*w2 minus a row constant -> same softmax).
//   Inner loop: 2 VALU/element (v_add + v_fma with abs modifier),
//   PF=8 float2 R-loads in flight, Lp via one b128 LDS broadcast per h.
// ---------------------------------------------------------------------------
__global__ __launch_bounds__(512) void adj_kernel(
    const float* __restrict__ Lp, const float* __restrict__ Rt,
    const float* __restrict__ W2, const float* __restrict__ c,
    float* __restrict__ out)
{
    constexpr int II = 4, PF = 8;
    __shared__ float LsT[H][4];
    __shared__ float sgn[H];
    __shared__ float red_m[II][8];
    __shared__ float red_s[II][8];

    const int t = threadIdx.x;
    const int lane = t & 63, wave = t >> 6;
    const int i0 = blockIdx.x * II;
    const int j0 = t * 2;

    if (t < H) {
        sgn[t] = (W2[t] >= 0.f) ? 0.5f : -0.5f;
        float4 lv;
        lv.x = Lp[(i0 + 0) * H + t];
        lv.y = Lp[(i0 + 1) * H + t];
        lv.z = Lp[(i0 + 2) * H + t];
        lv.w = Lp[(i0 + 3) * H + t];
        *reinterpret_cast<float4*>(&LsT[t][0]) = lv;
    }
    const float2 cj = *reinterpret_cast<const float2*>(&c[j0]);
    __syncthreads();

    float accx[II], accy[II];
#pragma unroll
    for (int ii = 0; ii < II; ++ii) { accx[ii] = cj.x; accy[ii] = cj.y; }

    float2 rbuf[PF];
#pragma unroll
    for (int p = 0; p < PF; ++p)
        rbuf[p] = *reinterpret_cast<const float2*>(&Rt[p * N + j0]);

    for (int hb = 0; hb < H - PF; hb += PF) {
#pragma unroll
        for (int p = 0; p < PF; ++p) {
            const int h = hb + p;
            const float2 r = rbuf[p];
            rbuf[p] = *reinterpret_cast<const float2*>(&Rt[(h + PF) * N + j0]);
            const float4 lv = *reinterpret_cast<const float4*>(&LsT[h][0]);
            const float s = sgn[h];
            const float* lp = &lv.x;
#pragma unroll
            for (int ii = 0; ii < II; ++ii) {
                accx[ii] = fmaf(s, fabsf(lp[ii] + r.x), accx[ii]);
                accy[ii] = fmaf(s, fabsf(lp[ii] + r.y), accy[ii]);
            }
        }
    }
#pragma unroll
    for (int p = 0; p < PF; ++p) {       // tail, no prefetch
        const int h = H - PF + p;
        const float2 r = rbuf[p];
        const float4 lv = *reinterpret_cast<const float4*>(&LsT[h][0]);
        const float s = sgn[h];
        const float* lp = &lv.x;
#pragma unroll
        for (int ii = 0; ii < II; ++ii) {
            accx[ii] = fmaf(s, fabsf(lp[ii] + r.x), accx[ii]);
            accy[ii] = fmaf(s, fabsf(lp[ii] + r.y), accy[ii]);
        }
    }

    // ---- softmax over j (block = full row) ----
#pragma unroll
    for (int ii = 0; ii < II; ++ii) {
        float m = fmaxf(accx[ii], accy[ii]);
#pragma unroll
        for (int off = 32; off; off >>= 1) m = fmaxf(m, __shfl_xor(m, off));
        if (lane == 0) red_m[ii][wave] = m;
    }
    __syncthreads();

    float mm[II];
#pragma unroll
    for (int ii = 0; ii < II; ++ii) {
        float m = red_m[ii][0];
#pragma unroll
        for (int w = 1; w < 8; ++w) m = fmaxf(m, red_m[ii][w]);
        mm[ii] = m;
    }

#pragma unroll
    for (int ii = 0; ii < II; ++ii) {
        accx[ii] = expf(accx[ii] - mm[ii]);
        accy[ii] = expf(accy[ii] - mm[ii]);
        float s = accx[ii] + accy[ii];
#pragma unroll
        for (int off = 32; off; off >>= 1) s += __shfl_xor(s, off);
        if (lane == 0) red_s[ii][wave] = s;
    }
    __syncthreads();

#pragma unroll
    for (int ii = 0; ii < II; ++ii) {
        float s = red_s[ii][0];
#pragma unroll
        for (int w = 1; w < 8; ++w) s += red_s[ii][w];
        const float r = 1.0f / s;
        float2 o;
        o.x = accx[ii] * r;
        o.y = accy[ii] * r;
        *reinterpret_cast<float2*>(&out[(i0 + ii) * N + j0]) = o;
    }
}

extern "C" void kernel_launch(void* const* d_in, const int* in_sizes, int n_in,
                              void* d_out, int out_size, void* d_ws, size_t ws_size,
                              hipStream_t stream) {
    const float* x  = (const float*)d_in[0];   // (N,H)
    const float* W1 = (const float*)d_in[1];   // (2H,H)
    const float* b1 = (const float*)d_in[2];   // (H,)
    const float* W2 = (const float*)d_in[3];   // (H,1)
    // d_in[4] = b2 — cancels under softmax, not needed.
    float* out = (float*)d_out;

    float* Lp = (float*)d_ws;        // N*H
    float* Rt = Lp + N * H;          // H*N (transposed, w2-scaled)
    float* cc = Rt + H * N;          // N

    prep_kernel<<<N / 4, 512, 0, stream>>>(x, W1, b1, W2, Lp, Rt, cc);
    adj_kernel<<<N / 4, 512, 0, stream>>>(Lp, Rt, W2, cc, out);
}